// Round 2
// baseline (1087.681 us; speedup 1.0000x reference)
//
#include <hip/hip_runtime.h>
#include <cstdint>
#include <cstddef>

typedef unsigned short u16;
typedef unsigned int u32;
typedef __attribute__((ext_vector_type(4))) float f32x4;
typedef __attribute__((ext_vector_type(8))) short s16x8;

#define DEVI static __device__ __forceinline__

// ---------- small helpers ----------
DEVI float bf2f(u16 v) { return __uint_as_float(((u32)v) << 16); }
DEVI u16 f2bf(float f) {             // RNE float->bf16
  u32 u = __float_as_uint(f);
  u = u + 0x7fffu + ((u >> 16) & 1u);
  return (u16)(u >> 16);
}
DEVI float gelu_f(float x) {         // tanh-approx gelu (|err| < ~1e-3 vs erf)
  float u = 0.7978845608028654f * (x + 0.044715f * x * x * x);
  float e = __expf(2.0f * u);
  float t = 1.0f - 2.0f / (e + 1.0f);
  return 0.5f * x * (1.0f + t);
}
DEVI void gload_lds16(const void* g, void* l) {
  __builtin_amdgcn_global_load_lds(
      (const __attribute__((address_space(1))) u32*)g,
      (__attribute__((address_space(3))) u32*)l, 16, 0, 0);
}

// ---------- LayerNorm (one wave per 256-wide row) ----------
template<int IN_BF16>
__global__ __launch_bounds__(256) void ln_kernel(
    const void* __restrict__ inv, const float* __restrict__ w,
    const float* __restrict__ b, u16* __restrict__ out, int nrows)
{
  const int wid = (blockIdx.x << 2) + (threadIdx.x >> 6);
  const int lane = threadIdx.x & 63;
  if (wid >= nrows) return;
  float v[4];
  if (IN_BF16) {
    const ushort4 raw = *((const ushort4*)inv + (size_t)wid * 64 + lane);
    v[0] = bf2f(raw.x); v[1] = bf2f(raw.y); v[2] = bf2f(raw.z); v[3] = bf2f(raw.w);
  } else {
    const float4 raw = *((const float4*)inv + (size_t)wid * 64 + lane);
    v[0] = raw.x; v[1] = raw.y; v[2] = raw.z; v[3] = raw.w;
  }
  float s = v[0] + v[1] + v[2] + v[3];
  #pragma unroll
  for (int m = 1; m < 64; m <<= 1) s += __shfl_xor(s, m, 64);
  const float mu = s * (1.0f / 256.0f);
  const float d0 = v[0] - mu, d1 = v[1] - mu, d2 = v[2] - mu, d3 = v[3] - mu;
  float q = d0 * d0 + d1 * d1 + d2 * d2 + d3 * d3;
  #pragma unroll
  for (int m = 1; m < 64; m <<= 1) q += __shfl_xor(q, m, 64);
  const float rstd = rsqrtf(q * (1.0f / 256.0f) + 1e-6f);
  const int c = lane << 2;
  ushort4 o;
  o.x = f2bf(d0 * rstd * w[c + 0] + b[c + 0]);
  o.y = f2bf(d1 * rstd * w[c + 1] + b[c + 1]);
  o.z = f2bf(d2 * rstd * w[c + 2] + b[c + 2]);
  o.w = f2bf(d3 * rstd * w[c + 3] + b[c + 3]);
  *((ushort4*)out + (size_t)wid * 64 + lane) = o;
}

// ---------- f32 -> bf16 weight convert ----------
__global__ __launch_bounds__(256) void cvt_kernel(
    const float* __restrict__ in, u16* __restrict__ out, int n)
{
  const int i = blockIdx.x * 256 + threadIdx.x;
  if (i < n) out[i] = f2bf(in[i]);
}

// ---------- GEMM: C[m,n] = sum_k A[m,k]*Bw[n,k] (+bias, epilogue) ----------
// m97 structure: 128x128 tile, BK=64, 4 waves (2x2), mfma 16x16x32 bf16.
// Staging via global_load_lds(16B) with source-side XOR swizzle:
//   LDS chunk (r,c') holds global chunk (r, c'^(r&7)); reads XOR the same way.
// EPI: 0 = bias -> bf16 ; 1 = bias+gelu -> bf16 ;
//      2 = bias + f32 residual -> bf16 ; 3 = bias + bf16 residual -> f32
template<int EPI>
__global__ __launch_bounds__(256) void gemm_bt(
    const u16* __restrict__ A, const u16* __restrict__ Bw,
    const float* __restrict__ bias, const void* __restrict__ res,
    void* __restrict__ Cout, int M, int N, int K)
{
  __shared__ u16 lds[16384];  // A: [0,8192), B: [8192,16384)  (32 KiB)
  const int tid = threadIdx.x;
  const int lane = tid & 63;
  const int wave = tid >> 6;
  const int wr = wave >> 1;
  const int wc = wave & 1;
  const int mtile = blockIdx.y;
  const int ntile = blockIdx.x;

  const u16* Abase = A + (size_t)mtile * 128 * K;
  const u16* Bbase = Bw + (size_t)ntile * 128 * K;

  f32x4 acc[4][4] = {};

  const int nk = K >> 6;
  for (int kt = 0; kt < nk; ++kt) {
    const int k0 = kt << 6;
    #pragma unroll
    for (int i = 0; i < 4; ++i) {          // stage A tile (128x64)
      const int L = i * 256 + tid;
      const int r = L >> 3;
      const int c = (L & 7) ^ (r & 7);
      gload_lds16(Abase + (size_t)r * K + k0 + c * 8,
                  &lds[(i * 256 + (wave << 6)) * 8]);
    }
    #pragma unroll
    for (int i = 0; i < 4; ++i) {          // stage B tile (128x64)
      const int L = i * 256 + tid;
      const int r = L >> 3;
      const int c = (L & 7) ^ (r & 7);
      gload_lds16(Bbase + (size_t)r * K + k0 + c * 8,
                  &lds[8192 + (i * 256 + (wave << 6)) * 8]);
    }
    __syncthreads();
    #pragma unroll
    for (int kk = 0; kk < 2; ++kk) {
      s16x8 af[4], bfv[4];
      #pragma unroll
      for (int i = 0; i < 4; ++i) {
        const int row = (wr << 6) + (i << 4) + (lane & 15);
        const int cc = ((kk << 2) + (lane >> 4)) ^ (row & 7);
        af[i] = *(const s16x8*)&lds[row * 64 + cc * 8];
      }
      #pragma unroll
      for (int j = 0; j < 4; ++j) {
        const int row = (wc << 6) + (j << 4) + (lane & 15);
        const int cc = ((kk << 2) + (lane >> 4)) ^ (row & 7);
        bfv[j] = *(const s16x8*)&lds[8192 + row * 64 + cc * 8];
      }
      #pragma unroll
      for (int i = 0; i < 4; ++i)
        #pragma unroll
        for (int j = 0; j < 4; ++j)
          acc[i][j] = __builtin_amdgcn_mfma_f32_16x16x32_bf16(af[i], bfv[j], acc[i][j], 0, 0, 0);
    }
    __syncthreads();
  }

  // epilogue; C/D layout: col = lane&15, row = (lane>>4)*4 + p
  #pragma unroll
  for (int j = 0; j < 4; ++j) {
    const int col = (ntile << 7) + (wc << 6) + (j << 4) + (lane & 15);
    const float bv = bias[col];
    #pragma unroll
    for (int i = 0; i < 4; ++i) {
      const int rbase = (mtile << 7) + (wr << 6) + (i << 4) + ((lane >> 4) << 2);
      #pragma unroll
      for (int p = 0; p < 4; ++p) {
        const size_t off = (size_t)(rbase + p) * N + col;
        float v = acc[i][j][p] + bv;
        if (EPI == 0) {
          ((u16*)Cout)[off] = f2bf(v);
        } else if (EPI == 1) {
          ((u16*)Cout)[off] = f2bf(gelu_f(v));
        } else if (EPI == 2) {
          v += ((const float*)res)[off];
          ((u16*)Cout)[off] = f2bf(v);
        } else {
          v += bf2f(((const u16*)res)[off]);
          ((float*)Cout)[off] = v;
        }
      }
    }
  }
}

// ---------- tiny T=3 attention, one thread per (row, head) ----------
DEVI void load32bf(float* dst, const u16* p) {
  #pragma unroll
  for (int i = 0; i < 4; ++i) {
    const uint4 r = *(const uint4*)(p + i * 8);
    const u32 w0 = r.x, w1 = r.y, w2 = r.z, w3 = r.w;
    dst[i*8+0] = bf2f((u16)(w0 & 0xffffu)); dst[i*8+1] = bf2f((u16)(w0 >> 16));
    dst[i*8+2] = bf2f((u16)(w1 & 0xffffu)); dst[i*8+3] = bf2f((u16)(w1 >> 16));
    dst[i*8+4] = bf2f((u16)(w2 & 0xffffu)); dst[i*8+5] = bf2f((u16)(w2 >> 16));
    dst[i*8+6] = bf2f((u16)(w3 & 0xffffu)); dst[i*8+7] = bf2f((u16)(w3 >> 16));
  }
}

// kvq rows are chunk-local: 37632 rows = 4 groups x (3 t x 3136 hw).
// Row layout of kvq: [0,256)=k, [256,512)=v, [512,768)=q, each 8 heads x 32.
__global__ __launch_bounds__(256) void attn_kernel(
    const u16* __restrict__ kvq, u16* __restrict__ aout, int nrows)
{
  const int t = blockIdx.x * 256 + threadIdx.x;
  if (t >= nrows * 8) return;
  const int lr = t >> 3;
  const int h = t & 7;
  const int gl = lr / 9408;
  const int rem = lr - gl * 9408;
  const int hw = rem % 3136;
  const int base = gl * 9408 + hw;

  float q[32];
  load32bf(q, kvq + (size_t)lr * 768 + 512 + h * 32);

  float l[3];
  #pragma unroll
  for (int tk = 0; tk < 3; ++tk) {
    float kv[32];
    load32bf(kv, kvq + (size_t)(base + tk * 3136) * 768 + h * 32);
    float a = 0.f;
    #pragma unroll
    for (int i = 0; i < 32; ++i) a += q[i] * kv[i];
    l[tk] = a * 0.17677669529663687f;   // 1/sqrt(32)
  }
  const float m = fmaxf(l[0], fmaxf(l[1], l[2]));
  const float e0 = __expf(l[0] - m), e1 = __expf(l[1] - m), e2 = __expf(l[2] - m);
  const float inv = 1.0f / (e0 + e1 + e2);
  const float ew[3] = {e0 * inv, e1 * inv, e2 * inv};

  float o[32] = {};
  #pragma unroll
  for (int tk = 0; tk < 3; ++tk) {
    float kv[32];
    load32bf(kv, kvq + (size_t)(base + tk * 3136) * 768 + 256 + h * 32);
    #pragma unroll
    for (int i = 0; i < 32; ++i) o[i] += ew[tk] * kv[i];
  }
  u16* op = aout + (size_t)lr * 256 + h * 32;
  #pragma unroll
  for (int i = 0; i < 4; ++i) {
    uint4 r;
    r.x = (u32)f2bf(o[i*8+0]) | ((u32)f2bf(o[i*8+1]) << 16);
    r.y = (u32)f2bf(o[i*8+2]) | ((u32)f2bf(o[i*8+3]) << 16);
    r.z = (u32)f2bf(o[i*8+4]) | ((u32)f2bf(o[i*8+5]) << 16);
    r.w = (u32)f2bf(o[i*8+6]) | ((u32)f2bf(o[i*8+7]) << 16);
    *(uint4*)(op + i * 8) = r;
  }
}

// ---------- launch ----------
// Sizes: ROWS=150528 (=48*56*56), C=256, hid=1024, kvq width 768.
// All GEMM dims divisible by tile sizes (150528/128=1176, 37632/128=294).
// ws layout (bytes):
//   [0,            77070336)  xn  (bf16 ROWSx256)   -> later reused as xt
//   [77070336,    154140672)  attn_out              -> later reused as xn2
//   [154140672,   231211008)  kvq chunk (37632x768) -> later reused as h chunk (37632x1024)
//   [231211008,   232783872)  bf16 weights (kvq_w, proj_w, fc1_w, fc2_w)
extern "C" void kernel_launch(void* const* d_in, const int* in_sizes, int n_in,
                              void* d_out, int out_size, void* d_ws, size_t ws_size,
                              hipStream_t stream) {
  const float* x    = (const float*)d_in[0];
  const float* n1w  = (const float*)d_in[1];
  const float* n1b  = (const float*)d_in[2];
  const float* kvqw = (const float*)d_in[3];
  const float* kvqb = (const float*)d_in[4];
  const float* pw   = (const float*)d_in[5];
  const float* pb   = (const float*)d_in[6];
  const float* n2w  = (const float*)d_in[7];
  const float* n2b  = (const float*)d_in[8];
  const float* f1w  = (const float*)d_in[9];
  const float* f1b  = (const float*)d_in[10];
  const float* f2w  = (const float*)d_in[11];
  const float* f2b  = (const float*)d_in[12];

  char* ws = (char*)d_ws;
  u16* xn     = (u16*)(ws + 0);
  u16* aout   = (u16*)(ws + 77070336);
  u16* kvqc   = (u16*)(ws + 154140672);
  u16* hbuf   = kvqc;      // 37632x1024 bf16 fits the same slot region
  u16* xt     = xn;        // xn dead after last kvq gemm
  u16* xn2    = aout;      // aout dead after proj
  u16* wbuf   = (u16*)(ws + 231211008);
  u16* kvqw_b = wbuf;              // 768*256   = 196608
  u16* pw_b   = wbuf + 196608;     // 256*256   =  65536
  u16* f1w_b  = wbuf + 262144;     // 1024*256  = 262144
  u16* f2w_b  = wbuf + 524288;     // 256*1024  = 262144

  // weights -> bf16
  cvt_kernel<<<768,  256, 0, stream>>>(kvqw, kvqw_b, 196608);
  cvt_kernel<<<256,  256, 0, stream>>>(pw,   pw_b,   65536);
  cvt_kernel<<<1024, 256, 0, stream>>>(f1w,  f1w_b,  262144);
  cvt_kernel<<<1024, 256, 0, stream>>>(f2w,  f2w_b,  262144);

  // LN1: x (f32) -> xn (bf16)
  ln_kernel<0><<<37632, 256, 0, stream>>>(x, n1w, n1b, xn, 150528);

  // kvq GEMM + attention, 4 chunks of 4 batch-groups (37632 rows) each
  for (int c = 0; c < 4; ++c) {
    const size_t r0 = (size_t)c * 37632;
    gemm_bt<0><<<dim3(6, 294), 256, 0, stream>>>(
        xn + r0 * 256, kvqw_b, kvqb, nullptr, kvqc, 37632, 768, 256);
    attn_kernel<<<1176, 256, 0, stream>>>(kvqc, aout + r0 * 256, 37632);
  }

  // proj + bias + residual(x) -> xt (bf16)
  gemm_bt<2><<<dim3(2, 1176), 256, 0, stream>>>(
      aout, pw_b, pb, x, xt, 150528, 256, 256);

  // LN2: xt (bf16) -> xn2 (bf16)
  ln_kernel<1><<<37632, 256, 0, stream>>>(xt, n2w, n2b, xn2, 150528);

  // MLP per M-chunk: fc1+gelu -> h ; fc2 + bias + residual(xt) -> out (f32)
  for (int c = 0; c < 4; ++c) {
    const size_t r0 = (size_t)c * 37632;
    gemm_bt<1><<<dim3(8, 294), 256, 0, stream>>>(
        xn2 + r0 * 256, f1w_b, f1b, nullptr, hbuf, 37632, 1024, 256);
    gemm_bt<3><<<dim3(2, 294), 256, 0, stream>>>(
        hbuf, f2w_b, f2b, xt + r0 * 256, (float*)d_out + r0 * 256, 37632, 256, 1024);
  }
}